// Round 3
// baseline (1392.714 us; speedup 1.0000x reference)
//
#include <hip/hip_runtime.h>

// Masked inclusive cumsum along rows (2048 x 32768 fp32), single-pass chained scan.
//
// R2 post-mortem: one 1024-thread block per row was latency-bound (3 TB/s,
// VALUBusy 7.5%) -- compiler capped VGPRs at 44 (no up-front MLP), and 16-wave
// lockstep phases left the memory pipe idle during scan/store with only 2
// resident blocks/CU.
//
// R3: 8 segments/row x 2048 rows = 16384 blocks of 256 threads (4 waves).
// 32 payload VGPRs -> 8 blocks/CU resident; blocks in different phases
// overlap, memory pipe stays busy. Cross-segment carry via chained
// decoupled-lookback: entry[seg*2048+row] = u64{hi=1 ready, lo=float bits of
// inclusive prefix}. Segment-major block ordering => predecessors dispatched
// a full generation earlier; spin is ~zero. Flags zeroed per launch with
// hipMemsetAsync (graph-capturable, stream-ordered).

#define ROWS    2048
#define NCOL    32768
#define SEGCOL  4096
#define NSEG    (NCOL / SEGCOL)            // 8
#define THREADS 256
#define CPT     4                          // float4 chunks per thread
#define NCH     (THREADS * CPT)            // 1024 chunk sums per segment
#define PAD(i)  ((i) + ((i) >> 2))         // LDS pad: stride-4 reads -> stride 5

__global__ __launch_bounds__(THREADS, 8) void mcs_chain(
    const float* __restrict__ x,
    const int*   __restrict__ mask,
    float*       __restrict__ out,
    unsigned long long* __restrict__ done)
{
    const int bid = blockIdx.x;
    const int seg = bid >> 11;             // blockIdx = seg*2048 + row
    const int row = bid & 2047;
    const size_t base = (size_t)row * NCOL + (size_t)seg * SEGCOL;
    const float4* __restrict__ xs = (const float4*)(x + base);
    const int4*   __restrict__ ms = (const int4*)(mask + base);
    float4*       __restrict__ os = (float4*)(out + base);

    const int tid  = threadIdx.x;
    const int lane = tid & 63;
    const int wave = tid >> 6;

    __shared__ float csum[PAD(NCH - 1) + 2];
    __shared__ float wtot[4];
    __shared__ float bcast;

    // ---- Load segment (8 independent vector loads, 32 payload VGPRs)
    float4 xv[CPT];
    int4   mv[CPT];
    #pragma unroll
    for (int k = 0; k < CPT; ++k) {
        xv[k] = xs[k * THREADS + tid];
        mv[k] = ms[k * THREADS + tid];
    }

    // ---- Mask + per-chunk inclusive prefix (reuses xv's registers)
    float4 p[CPT];
    #pragma unroll
    for (int k = 0; k < CPT; ++k) {
        float a0 = mv[k].x ? xv[k].x : 0.0f;
        float a1 = mv[k].y ? xv[k].y : 0.0f;
        float a2 = mv[k].z ? xv[k].z : 0.0f;
        float a3 = mv[k].w ? xv[k].w : 0.0f;
        p[k].x = a0;
        p[k].y = p[k].x + a1;
        p[k].z = p[k].y + a2;
        p[k].w = p[k].z + a3;
        int c = k * THREADS + tid;
        csum[PAD(c)] = p[k].w;             // lane stride 1 (+bump) -> <=2-way, free
    }
    __syncthreads();

    // ---- Block scan over 1024 chunk sums
    // thread j owns chunks 4j..4j+3: padded stride 5 -> conflict-free
    float s[CPT];
    float run = 0.0f;
    #pragma unroll
    for (int k = 0; k < CPT; ++k) {
        run += csum[PAD(tid * CPT + k)];
        s[k] = run;
    }

    float sc = run;                        // wave-64 inclusive scan
    #pragma unroll
    for (int d = 1; d < 64; d <<= 1) {
        float o = __shfl_up(sc, d);
        if (lane >= d) sc += o;
    }
    if (lane == 63) wtot[wave] = sc;
    __syncthreads();

    float woff = 0.0f;
    #pragma unroll
    for (int w = 0; w < 4; ++w)
        woff += (w < wave) ? wtot[w] : 0.0f;
    const float thr_excl = woff + (sc - run);

    // Write exclusive chunk offsets back (same private slots)
    #pragma unroll
    for (int k = 0; k < CPT; ++k)
        csum[PAD(tid * CPT + k)] = thr_excl + (k ? s[k - 1] : 0.0f);

    // ---- Chained carry across segments (thread 0)
    if (tid == 0) {
        float btot = wtot[0] + wtot[1] + wtot[2] + wtot[3];
        float excl = 0.0f;
        if (seg != 0) {
            const unsigned long long* pred = done + (bid - ROWS);
            unsigned long long v;
            do {
                v = __hip_atomic_load(pred, __ATOMIC_ACQUIRE,
                                      __HIP_MEMORY_SCOPE_AGENT);
                if ((v >> 32) == 1ull) break;
                __builtin_amdgcn_s_sleep(1);
            } while (true);
            excl = __uint_as_float((unsigned)v);
        }
        unsigned long long pv =
            (1ull << 32) | (unsigned long long)__float_as_uint(excl + btot);
        __hip_atomic_store(done + bid, pv, __ATOMIC_RELEASE,
                           __HIP_MEMORY_SCOPE_AGENT);
        bcast = excl;
    }
    __syncthreads();

    // ---- Add offsets, store
    const float ro = bcast;
    #pragma unroll
    for (int k = 0; k < CPT; ++k) {
        int c = k * THREADS + tid;
        float off = ro + csum[PAD(c)];
        os[c] = make_float4(off + p[k].x, off + p[k].y, off + p[k].z,
                            off + p[k].w);
    }
}

// ---------------- Fallback (R2 structure) if ws is too small ----------------
#define FB_THREADS 1024
#define FB_TILES   8
#define FB_NCHUNK  (FB_THREADS * FB_TILES)

__global__ __launch_bounds__(FB_THREADS, 1) void mcs_fallback(
    const float* __restrict__ x, const int* __restrict__ mask,
    float* __restrict__ out)
{
    const int row = blockIdx.x;
    const size_t base = (size_t)row * NCOL;
    const float4* xrow = (const float4*)(x + base);
    const int4*   mrow = (const int4*)(mask + base);
    float4*       orow = (float4*)(out + base);
    const int tid = threadIdx.x, lane = tid & 63, wave = tid >> 6;
    __shared__ float csum[FB_NCHUNK + FB_NCHUNK / 8];
    __shared__ float wt[16];
    float4 xv[FB_TILES]; int4 mv[FB_TILES];
    #pragma unroll
    for (int t = 0; t < FB_TILES; ++t) {
        xv[t] = xrow[t * FB_THREADS + tid];
        mv[t] = mrow[t * FB_THREADS + tid];
    }
    float4 p[FB_TILES];
    #pragma unroll
    for (int t = 0; t < FB_TILES; ++t) {
        float a0 = mv[t].x ? xv[t].x : 0.f, a1 = mv[t].y ? xv[t].y : 0.f;
        float a2 = mv[t].z ? xv[t].z : 0.f, a3 = mv[t].w ? xv[t].w : 0.f;
        p[t].x = a0; p[t].y = p[t].x + a1; p[t].z = p[t].y + a2; p[t].w = p[t].z + a3;
        int c = t * FB_THREADS + tid;
        csum[c + (c >> 3)] = p[t].w;
    }
    __syncthreads();
    float s[8], run = 0.f;
    #pragma unroll
    for (int k = 0; k < 8; ++k) { run += csum[tid * 9 + k]; s[k] = run; }
    float sc = run;
    #pragma unroll
    for (int d = 1; d < 64; d <<= 1) { float o = __shfl_up(sc, d); if (lane >= d) sc += o; }
    if (lane == 63) wt[wave] = sc;
    __syncthreads();
    float woff = 0.f;
    #pragma unroll
    for (int w = 0; w < 16; ++w) woff += (w < wave) ? wt[w] : 0.f;
    const float te = woff + (sc - run);
    #pragma unroll
    for (int k = 0; k < 8; ++k) csum[tid * 9 + k] = te + (k ? s[k - 1] : 0.f);
    __syncthreads();
    #pragma unroll
    for (int t = 0; t < FB_TILES; ++t) {
        int c = t * FB_THREADS + tid;
        float off = csum[c + (c >> 3)];
        orow[c] = make_float4(off + p[t].x, off + p[t].y, off + p[t].z, off + p[t].w);
    }
}

extern "C" void kernel_launch(void* const* d_in, const int* in_sizes, int n_in,
                              void* d_out, int out_size, void* d_ws, size_t ws_size,
                              hipStream_t stream) {
    const float* x    = (const float*)d_in[0];
    const int*   mask = (const int*)d_in[1];
    float*       out  = (float*)d_out;
    const size_t flag_bytes = (size_t)NSEG * ROWS * sizeof(unsigned long long);

    if (d_ws != nullptr && ws_size >= flag_bytes) {
        hipMemsetAsync(d_ws, 0, flag_bytes, stream);
        mcs_chain<<<NSEG * ROWS, THREADS, 0, stream>>>(
            x, mask, out, (unsigned long long*)d_ws);
    } else {
        mcs_fallback<<<ROWS, FB_THREADS, 0, stream>>>(x, mask, out);
    }
}